// Round 11
// baseline (268.757 us; speedup 1.0000x reference)
//
#include <hip/hip_runtime.h>

#define BATCH 8
#define HH 768
#define WW 1024
#define HW (HH*WW)
#define NPIX (BATCH*HW)            /* 6291456 */
#define RG 81
#define KG (2*RG+1)                /* 163 */
#define INVK2 (1.0f/((float)KG*(float)KG))
#define RM 7
#define EPSF 1e-3f
#define NBINS 2000
#define NEG_BIG_F (-1.0e30f)
#define NROWS (BATCH*HH)           /* 6144 row-blocks */

#define BH 48                      /* band height for row-major vertical passes */
#define NBAND (HH/BH)              /* 16 bands */
#define NVB 512                    /* 8 img x 16 bands x 4 col-quarters */
#define CHM 32
#define NCHM (HH/CHM)              /* 24 chunks for vertical min filter */

/* ---------------- helpers ---------------- */

__device__ inline unsigned fkey(float f) {
    unsigned u = __float_as_uint(f);
    return (u & 0x80000000u) ? ~u : (u | 0x80000000u);
}
__device__ inline float funkey(unsigned k) {
    unsigned u = (k & 0x80000000u) ? (k & 0x7fffffffu) : ~k;
    return __uint_as_float(u);
}

/* band decode for vertical passes: XCD (blockIdx%8) owns image (blockIdx%8);
   128 threads x 2 cols = 256-col quarter; 16 bands of 48 rows. */
__device__ inline void bandDecode(int idx, int& img, int& c0, int& h0) {
    img = idx & 7;
    int j = idx >> 3;          /* 0..63 */
    int colq = j >> 4;         /* 0..3 */
    int band = j & 15;         /* 0..15 */
    c0 = colq * 256 + threadIdx.x * 2;
    h0 = band * BH;
}

__device__ inline float waveInclScan(float x) {
    int lane = threadIdx.x & 63;
#pragma unroll
    for (int d = 1; d < 64; d <<= 1) {
        float u = __shfl_up(x, (unsigned)d, 64);
        if (lane >= d) x += u;
    }
    return x;
}

/* inclusive prefix over 1024 row elements (4 per thread), result into cum[0..1023] */
__device__ inline void scanRow(float v0, float v1, float v2, float v3,
                               float* cum, float* wsum) {
    int tid = threadIdx.x;
    float c0 = v0, c1 = c0 + v1, c2 = c1 + v2, c3 = c2 + v3;
    float inc = waveInclScan(c3);
    int lane = tid & 63, wv = tid >> 6;
    if (lane == 63) wsum[wv] = inc;
    __syncthreads();
    float basev = 0.f;
    if (wv > 0) basev += wsum[0];
    if (wv > 1) basev += wsum[1];
    if (wv > 2) basev += wsum[2];
    float ex = basev + inc - c3;
    cum[4 * tid + 0] = ex + c0;
    cum[4 * tid + 1] = ex + c1;
    cum[4 * tid + 2] = ex + c2;
    cum[4 * tid + 3] = ex + c3;
}

/* ---------------- kernels ---------------- */

__global__ void k_init(unsigned* scal, unsigned* hist) {
    int t = threadIdx.x;
    for (int i = t; i < NBINS; i += 256) hist[i] = 0u;
    if (t == 0) {
        scal[0] = 0xFFFFFFFFu;  /* minKey */
        scal[1] = 0u;           /* maxKey */
        scal[2] = 0u;           /* A-cand key */
        scal[3] = 0u;           /* any flag */
    }
}

/* dark channel + channel mean + per-block partial sums + fused horizontal
   min filter (block == one image row). */
__global__ __launch_bounds__(256) void k_prep(const float* __restrict__ x,
                                              float* __restrict__ V1raw,
                                              float* __restrict__ mmean,
                                              float* __restrict__ hmin,
                                              float* __restrict__ pbsum) {
    int img = blockIdx.x / HH;
    int row = blockIdx.x % HH;
    int pix = row * WW + threadIdx.x * 4;
    size_t base = (size_t)img * 3 * HW + pix;
    float4 c0 = *(const float4*)(x + base);
    float4 c1 = *(const float4*)(x + base + HW);
    float4 c2 = *(const float4*)(x + base + 2 * (size_t)HW);
    float4 mnv, mev;
    {
        float a0 = c0.x * 255.0f, a1 = c1.x * 255.0f, a2 = c2.x * 255.0f;
        mnv.x = fminf(a0, fminf(a1, a2)); mev.x = (a0 + a1 + a2) * (1.0f / 3.0f);
        a0 = c0.y * 255.0f; a1 = c1.y * 255.0f; a2 = c2.y * 255.0f;
        mnv.y = fminf(a0, fminf(a1, a2)); mev.y = (a0 + a1 + a2) * (1.0f / 3.0f);
        a0 = c0.z * 255.0f; a1 = c1.z * 255.0f; a2 = c2.z * 255.0f;
        mnv.z = fminf(a0, fminf(a1, a2)); mev.z = (a0 + a1 + a2) * (1.0f / 3.0f);
        a0 = c0.w * 255.0f; a1 = c1.w * 255.0f; a2 = c2.w * 255.0f;
        mnv.w = fminf(a0, fminf(a1, a2)); mev.w = (a0 + a1 + a2) * (1.0f / 3.0f);
    }
    size_t po = (size_t)img * HW + pix;
    *(float4*)(V1raw + po) = mnv;
    *(float4*)(mmean + po) = mev;

    __shared__ float r[WW];
    int t = threadIdx.x;
    r[4 * t + 0] = mnv.x; r[4 * t + 1] = mnv.y; r[4 * t + 2] = mnv.z; r[4 * t + 3] = mnv.w;

    float s = mev.x + mev.y + mev.z + mev.w;
#pragma unroll
    for (int d = 32; d >= 1; d >>= 1) s += __shfl_down(s, (unsigned)d, 64);
    __shared__ float wsum[4];
    int lane = t & 63, wv = t >> 6;
    if (lane == 0) wsum[wv] = s;
    __syncthreads();
    if (t == 0)
        pbsum[blockIdx.x] = wsum[0] + wsum[1] + wsum[2] + wsum[3];

    /* horizontal min cascade (r=7) */
    float v[18];
#pragma unroll
    for (int i = 0; i < 18; i++) {
        int w = 4 * t - RM + i;
        w = w < 0 ? 0 : (w > WW - 1 ? WW - 1 : w);
        v[i] = r[w];
    }
#pragma unroll
    for (int i = 0; i < 17; i++) v[i] = fminf(v[i], v[i + 1]);   /* w2 */
#pragma unroll
    for (int i = 0; i < 15; i++) v[i] = fminf(v[i], v[i + 2]);   /* w4 */
#pragma unroll
    for (int i = 0; i < 11; i++) v[i] = fminf(v[i], v[i + 4]);   /* w8 */
    float4 o;
    o.x = fminf(v[0], v[7]);
    o.y = fminf(v[1], v[8]);
    o.z = fminf(v[2], v[9]);
    o.w = fminf(v[3], v[10]);
    *(float4*)(hmin + po) = o;
}

/* vertical min filter (r=7), thread per (col, 32-row chunk), log-cascade */
__global__ __launch_bounds__(256) void k_minv(const float* __restrict__ in,
                                              float* __restrict__ out) {
    int g = blockIdx.x * 256 + threadIdx.x;
    int w = g & (WW - 1);
    int t = g >> 10;
    int b = t / NCHM;
    int ch = t - b * NCHM;
    int h0 = ch * CHM;
    const float* col = in + (size_t)b * HW + w;
    float* ocol = out + (size_t)b * HW + w;
    float v[CHM + 14];
#pragma unroll
    for (int i = 0; i < CHM + 14; i++) {
        int h = h0 - RM + i;
        h = h < 0 ? 0 : (h > HH - 1 ? HH - 1 : h);
        v[i] = col[(size_t)h * WW];
    }
#pragma unroll
    for (int i = 0; i < CHM + 13; i++) v[i] = fminf(v[i], v[i + 1]);   /* w2 */
#pragma unroll
    for (int i = 0; i < CHM + 11; i++) v[i] = fminf(v[i], v[i + 2]);   /* w4 */
#pragma unroll
    for (int i = 0; i < CHM + 7; i++)  v[i] = fminf(v[i], v[i + 4]);   /* w8 */
#pragma unroll
    for (int i = 0; i < CHM; i++)
        ocol[(size_t)(h0 + i) * WW] = fminf(v[i], v[i + 7]);           /* w15 */
}

/* GF vertical pass 1, row-major bands: running column sums of I, p, I*p, I*I.
   Block = 48-row band x 256 cols; thread owns 2 adjacent columns; all global
   accesses are contiguous row segments. OOB add/sub rows are zero-masked. */
__global__ __launch_bounds__(128) void k_kv1(const float* __restrict__ I,
                                             const float* __restrict__ p,
                                             float4* __restrict__ F4) {
    int img, c0, h0;
    bandDecode(blockIdx.x, img, c0, h0);
    const float* bI = I + (size_t)img * HW + c0;
    const float* bP = p + (size_t)img * HW + c0;
    float4* bO = F4 + (size_t)img * HW + c0;

    float4 A0 = {0,0,0,0}, A1 = {0,0,0,0};   /* {sI,sP,sIp,sII} for col0, col1 */
    int jlo = h0 - RG; if (jlo < 0) jlo = 0;
    int jhi = h0 + RG - 1; if (jhi > HH - 1) jhi = HH - 1;
    {
        float2 Li[8], Lp[8];
        int j = jlo;
        for (; j + 7 <= jhi; j += 8) {
#pragma unroll
            for (int k = 0; k < 8; k++) {
                Li[k] = *(const float2*)(bI + (size_t)(j + k) * WW);
                Lp[k] = *(const float2*)(bP + (size_t)(j + k) * WW);
            }
#pragma unroll
            for (int k = 0; k < 8; k++) {
                A0.x += Li[k].x; A0.y += Lp[k].x; A0.z += Li[k].x * Lp[k].x; A0.w += Li[k].x * Li[k].x;
                A1.x += Li[k].y; A1.y += Lp[k].y; A1.z += Li[k].y * Lp[k].y; A1.w += Li[k].y * Li[k].y;
            }
        }
        for (; j <= jhi; j++) {
            float2 a = *(const float2*)(bI + (size_t)j * WW);
            float2 c = *(const float2*)(bP + (size_t)j * WW);
            A0.x += a.x; A0.y += c.x; A0.z += a.x * c.x; A0.w += a.x * a.x;
            A1.x += a.y; A1.y += c.y; A1.z += a.y * c.y; A1.w += a.y * a.y;
        }
    }

    float2 Ai[8], Ap[8], Si[8], Sp[8];
    for (int h = h0; h < h0 + BH; h += 8) {
#pragma unroll
        for (int k = 0; k < 8; k++) {
            int ra = h + k + RG;
            int ca = ra <= HH - 1 ? ra : HH - 1;
            float2 a = *(const float2*)(bI + (size_t)ca * WW);
            float2 c = *(const float2*)(bP + (size_t)ca * WW);
            if (ra > HH - 1) { a = make_float2(0.f, 0.f); c = make_float2(0.f, 0.f); }
            Ai[k] = a; Ap[k] = c;
        }
#pragma unroll
        for (int k = 0; k < 8; k++) {
            int rs = h + k - RG;
            int cs = rs >= 0 ? rs : 0;
            float2 a = *(const float2*)(bI + (size_t)cs * WW);
            float2 c = *(const float2*)(bP + (size_t)cs * WW);
            if (rs < 0) { a = make_float2(0.f, 0.f); c = make_float2(0.f, 0.f); }
            Si[k] = a; Sp[k] = c;
        }
#pragma unroll
        for (int k = 0; k < 8; k++) {
            A0.x += Ai[k].x; A0.y += Ap[k].x; A0.z += Ai[k].x * Ap[k].x; A0.w += Ai[k].x * Ai[k].x;
            A1.x += Ai[k].y; A1.y += Ap[k].y; A1.z += Ai[k].y * Ap[k].y; A1.w += Ai[k].y * Ai[k].y;
            bO[(size_t)(h + k) * WW]     = A0;
            bO[(size_t)(h + k) * WW + 1] = A1;
            A0.x -= Si[k].x; A0.y -= Sp[k].x; A0.z -= Si[k].x * Sp[k].x; A0.w -= Si[k].x * Si[k].x;
            A1.x -= Si[k].y; A1.y -= Sp[k].y; A1.z -= Si[k].y * Sp[k].y; A1.w -= Si[k].y * Si[k].y;
        }
    }
}

/* GF horizontal pass: complete box1 sums via row scans -> a,b; then fuse
   box2's horizontal window: row scans of a,b -> windowed sums ha,hb. */
__global__ __launch_bounds__(256) void k_kh1(const float4* __restrict__ F4,
                                             float2* __restrict__ HAB) {
    __shared__ float cI[WW], cP[WW], cIp[WW], cII[WW];
    __shared__ float cA[WW], cB[WW];
    __shared__ float w0[4], w1[4], w2[4], w3[4], w4[4], w5[4];
    size_t base = (size_t)blockIdx.x * WW;
    int t = threadIdx.x;
    float4 q0 = F4[base + 4 * t + 0];
    float4 q1 = F4[base + 4 * t + 1];
    float4 q2 = F4[base + 4 * t + 2];
    float4 q3 = F4[base + 4 * t + 3];
    scanRow(q0.x, q1.x, q2.x, q3.x, cI, w0);
    scanRow(q0.y, q1.y, q2.y, q3.y, cP, w1);
    scanRow(q0.z, q1.z, q2.z, q3.z, cIp, w2);
    scanRow(q0.w, q1.w, q2.w, q3.w, cII, w3);
    __syncthreads();
    float av[4], bv[4];
#pragma unroll
    for (int j = 0; j < 4; j++) {
        int w = 4 * t + j;
        int hi = w + RG; if (hi > WW - 1) hi = WW - 1;
        int lo = w - RG - 1;
        float a = cI[hi], b = cP[hi], c = cIp[hi], d = cII[hi];
        if (lo >= 0) { a -= cI[lo]; b -= cP[lo]; c -= cIp[lo]; d -= cII[lo]; }
        float mI = a * INVK2, mP = b * INVK2, mIp = c * INVK2, mII = d * INVK2;
        float aa = (mIp - mI * mP) / ((mII - mI * mI) + EPSF);
        av[j] = aa; bv[j] = mP - aa * mI;
    }
    __syncthreads();   /* all reads of cI..cII done before any reuse barriers below */
    scanRow(av[0], av[1], av[2], av[3], cA, w4);
    scanRow(bv[0], bv[1], bv[2], bv[3], cB, w5);
    __syncthreads();
    float oa[4], ob[4];
#pragma unroll
    for (int j = 0; j < 4; j++) {
        int w = 4 * t + j;
        int hi = w + RG; if (hi > WW - 1) hi = WW - 1;
        int lo = w - RG - 1;
        float a = cA[hi], b = cB[hi];
        if (lo >= 0) { a -= cA[lo]; b -= cB[lo]; }
        oa[j] = a; ob[j] = b;
    }
    ((float4*)(HAB + base))[2 * t]     = make_float4(oa[0], ob[0], oa[1], ob[1]);
    ((float4*)(HAB + base))[2 * t + 1] = make_float4(oa[2], ob[2], oa[3], ob[3]);
}

/* GF vertical pass 2, row-major bands: sliding column sums of ha,hb;
   V1 = sum_a*INVK2*I + sum_b*INVK2; per-block min/max. */
__global__ __launch_bounds__(128) void k_kv2(const float2* __restrict__ HAB,
                                             const float* __restrict__ I,
                                             float* __restrict__ V1,
                                             float* __restrict__ bmin,
                                             float* __restrict__ bmax) {
    int img, c0, h0;
    bandDecode(blockIdx.x, img, c0, h0);
    const float2* bC = HAB + (size_t)img * HW + c0;
    const float* bI = I + (size_t)img * HW + c0;
    float* bV = V1 + (size_t)img * HW + c0;

    /* acc = {sa0, sb0, sa1, sb1} */
    float4 s0 = {0,0,0,0}, s1 = {0,0,0,0}, s2 = {0,0,0,0}, s3 = {0,0,0,0};
    int jlo = h0 - RG; if (jlo < 0) jlo = 0;
    int jhi = h0 + RG - 1; if (jhi > HH - 1) jhi = HH - 1;
    {
        float4 L[8];
        int j = jlo;
        for (; j + 7 <= jhi; j += 8) {
#pragma unroll
            for (int k = 0; k < 8; k++) L[k] = *(const float4*)(bC + (size_t)(j + k) * WW);
            s0.x += L[0].x; s0.y += L[0].y; s0.z += L[0].z; s0.w += L[0].w;
            s1.x += L[1].x; s1.y += L[1].y; s1.z += L[1].z; s1.w += L[1].w;
            s2.x += L[2].x; s2.y += L[2].y; s2.z += L[2].z; s2.w += L[2].w;
            s3.x += L[3].x; s3.y += L[3].y; s3.z += L[3].z; s3.w += L[3].w;
            s0.x += L[4].x; s0.y += L[4].y; s0.z += L[4].z; s0.w += L[4].w;
            s1.x += L[5].x; s1.y += L[5].y; s1.z += L[5].z; s1.w += L[5].w;
            s2.x += L[6].x; s2.y += L[6].y; s2.z += L[6].z; s2.w += L[6].w;
            s3.x += L[7].x; s3.y += L[7].y; s3.z += L[7].z; s3.w += L[7].w;
        }
        for (; j <= jhi; j++) {
            float4 v = *(const float4*)(bC + (size_t)j * WW);
            s0.x += v.x; s0.y += v.y; s0.z += v.z; s0.w += v.w;
        }
    }
    float4 acc;
    acc.x = (s0.x + s1.x) + (s2.x + s3.x);
    acc.y = (s0.y + s1.y) + (s2.y + s3.y);
    acc.z = (s0.z + s1.z) + (s2.z + s3.z);
    acc.w = (s0.w + s1.w) + (s2.w + s3.w);

    float lmn = 3.4e38f, lmx = -3.4e38f;
    float4 A[8], S[8];
    float2 Iv[8];
    for (int h = h0; h < h0 + BH; h += 8) {
#pragma unroll
        for (int k = 0; k < 8; k++) {
            int ra = h + k + RG;
            int ca = ra <= HH - 1 ? ra : HH - 1;
            float4 v = *(const float4*)(bC + (size_t)ca * WW);
            if (ra > HH - 1) v = make_float4(0.f, 0.f, 0.f, 0.f);
            A[k] = v;
        }
#pragma unroll
        for (int k = 0; k < 8; k++) {
            int rs = h + k - RG;
            int cs = rs >= 0 ? rs : 0;
            float4 v = *(const float4*)(bC + (size_t)cs * WW);
            if (rs < 0) v = make_float4(0.f, 0.f, 0.f, 0.f);
            S[k] = v;
        }
#pragma unroll
        for (int k = 0; k < 8; k++) Iv[k] = *(const float2*)(bI + (size_t)(h + k) * WW);
#pragma unroll
        for (int k = 0; k < 8; k++) {
            acc.x += A[k].x; acc.y += A[k].y; acc.z += A[k].z; acc.w += A[k].w;
            float v0 = acc.x * INVK2 * Iv[k].x + acc.y * INVK2;
            float v1 = acc.z * INVK2 * Iv[k].y + acc.w * INVK2;
            *(float2*)(bV + (size_t)(h + k) * WW) = make_float2(v0, v1);
            lmn = fminf(lmn, fminf(v0, v1));
            lmx = fmaxf(lmx, fmaxf(v0, v1));
            acc.x -= S[k].x; acc.y -= S[k].y; acc.z -= S[k].z; acc.w -= S[k].w;
        }
    }
#pragma unroll
    for (int d = 32; d >= 1; d >>= 1) {
        lmn = fminf(lmn, __shfl_down(lmn, (unsigned)d, 64));
        lmx = fmaxf(lmx, __shfl_down(lmx, (unsigned)d, 64));
    }
    __shared__ float smn[2], smx[2];
    int lane = threadIdx.x & 63, wv = threadIdx.x >> 6;
    if (lane == 0) { smn[wv] = lmn; smx[wv] = lmx; }
    __syncthreads();
    if (threadIdx.x == 0) {
        bmin[blockIdx.x] = fminf(smn[0], smn[1]);
        bmax[blockIdx.x] = fmaxf(smx[0], smx[1]);
    }
}

/* reduce per-block min/max -> scal keys (single block) */
__global__ __launch_bounds__(256) void k_mm(const float* __restrict__ bmin,
                                            const float* __restrict__ bmax,
                                            unsigned* __restrict__ scal) {
    float mn = 3.4e38f, mx = -3.4e38f;
    for (int i = threadIdx.x; i < NVB; i += 256) {
        mn = fminf(mn, bmin[i]);
        mx = fmaxf(mx, bmax[i]);
    }
#pragma unroll
    for (int d = 32; d >= 1; d >>= 1) {
        mn = fminf(mn, __shfl_down(mn, (unsigned)d, 64));
        mx = fmaxf(mx, __shfl_down(mx, (unsigned)d, 64));
    }
    __shared__ float smn[4], smx[4];
    int lane = threadIdx.x & 63, wv = threadIdx.x >> 6;
    if (lane == 0) { smn[wv] = mn; smx[wv] = mx; }
    __syncthreads();
    if (threadIdx.x == 0) {
        float a = fminf(fminf(smn[0], smn[1]), fminf(smn[2], smn[3]));
        float b = fmaxf(fmaxf(smx[0], smx[1]), fmaxf(smx[2], smx[3]));
        scal[0] = fkey(a);
        scal[1] = fkey(b);
    }
}

/* histogram (2000 bins over [mn,mx]), float4 reads */
__global__ __launch_bounds__(256) void k_hist(const float* __restrict__ V1,
                                              const unsigned* __restrict__ scal,
                                              unsigned* __restrict__ hist) {
    __shared__ unsigned lh[NBINS];
    for (int i = threadIdx.x; i < NBINS; i += 256) lh[i] = 0u;
    __syncthreads();
    float mn = funkey(scal[0]);
    float mx = funkey(scal[1]);
    float inv = 2000.0f / (mx - mn);
    const float4* V4 = (const float4*)V1;
    for (int i = blockIdx.x * 256 + threadIdx.x; i < NPIX / 4; i += gridDim.x * 256) {
        float4 v = V4[i];
        int i0 = (int)((v.x - mn) * inv); i0 = i0 < 0 ? 0 : (i0 > NBINS - 1 ? NBINS - 1 : i0);
        int i1 = (int)((v.y - mn) * inv); i1 = i1 < 0 ? 0 : (i1 > NBINS - 1 ? NBINS - 1 : i1);
        int i2 = (int)((v.z - mn) * inv); i2 = i2 < 0 ? 0 : (i2 > NBINS - 1 ? NBINS - 1 : i2);
        int i3 = (int)((v.w - mn) * inv); i3 = i3 < 0 ? 0 : (i3 > NBINS - 1 ? NBINS - 1 : i3);
        atomicAdd(&lh[i0], 1u);
        atomicAdd(&lh[i1], 1u);
        atomicAdd(&lh[i2], 1u);
        atomicAdd(&lh[i3], 1u);
    }
    __syncthreads();
    for (int i = threadIdx.x; i < NBINS; i += 256) {
        unsigned c = lh[i];
        if (c) atomicAdd(&hist[i], c);
    }
}

/* cumulative -> threshold (count at 99.9% bin), parallel block scan */
__global__ __launch_bounds__(256) void k_thresh(const unsigned* __restrict__ hist,
                                                float* __restrict__ fscal) {
    int t = threadIdx.x;
    unsigned h[8];
    float local = 0.f;
#pragma unroll
    for (int j = 0; j < 8; j++) {
        int idx = t * 8 + j;
        h[j] = (idx < NBINS) ? hist[idx] : 0u;
        local += (float)h[j];
    }
    float inc = waveInclScan(local);
    __shared__ float wsum[4];
    __shared__ int smax[4];
    int lane = t & 63, wv = t >> 6;
    if (lane == 63) wsum[wv] = inc;
    __syncthreads();
    float basev = 0.f;
    if (wv > 0) basev += wsum[0];
    if (wv > 1) basev += wsum[1];
    if (wv > 2) basev += wsum[2];
    float cum = basev + inc - local;   /* exclusive prefix; exact (integers < 2^24) */
    int lmax = -1;
#pragma unroll
    for (int j = 0; j < 8; j++) {
        int idx = t * 8 + j;
        cum += (float)h[j];
        float d = cum / (float)NPIX;
        if (idx < NBINS && d <= 0.999f) lmax = idx;
    }
#pragma unroll
    for (int d = 32; d >= 1; d >>= 1) {
        int o = __shfl_down(lmax, (unsigned)d, 64);
        lmax = o > lmax ? o : lmax;
    }
    if (lane == 0) smax[wv] = lmax;
    __syncthreads();
    if (t == 0) {
        int m = smax[0];
        if (smax[1] > m) m = smax[1];
        if (smax[2] > m) m = smax[2];
        if (smax[3] > m) m = smax[3];
        int idx = m < 0 ? NBINS - 1 : m;  /* hist[-1] wraps in the reference */
        fscal[4] = (float)hist[idx];
    }
}

/* masked max of channel-mean where V1 >= thresh, plus any(mask) */
__global__ __launch_bounds__(256) void k_amax(const float* __restrict__ V1,
                                              const float* __restrict__ mmean,
                                              const float* __restrict__ fscal,
                                              unsigned* __restrict__ scal) {
    float th = fscal[4];
    float lmax = NEG_BIG_F;
    bool any = false;
    const float4* V4 = (const float4*)V1;
    const float4* M4 = (const float4*)mmean;
    for (int i = blockIdx.x * 256 + threadIdx.x; i < NPIX / 4; i += gridDim.x * 256) {
        float4 v = V4[i];
        if (v.x >= th || v.y >= th || v.z >= th || v.w >= th) {
            float4 m = M4[i];
            any = true;
            if (v.x >= th) lmax = fmaxf(lmax, m.x);
            if (v.y >= th) lmax = fmaxf(lmax, m.y);
            if (v.z >= th) lmax = fmaxf(lmax, m.z);
            if (v.w >= th) lmax = fmaxf(lmax, m.w);
        }
    }
#pragma unroll
    for (int d = 32; d >= 1; d >>= 1) lmax = fmaxf(lmax, __shfl_down(lmax, (unsigned)d, 64));
    unsigned long long ab = __ballot(any);
    __shared__ float smx[4];
    __shared__ unsigned sany[4];
    int lane = threadIdx.x & 63, wv = threadIdx.x >> 6;
    if (lane == 0) { smx[wv] = lmax; sany[wv] = ab ? 1u : 0u; }
    __syncthreads();
    if (threadIdx.x == 0) {
        float m = fmaxf(fmaxf(smx[0], smx[1]), fmaxf(smx[2], smx[3]));
        unsigned a = sany[0] | sany[1] | sany[2] | sany[3];
        if (a) {
            atomicOr(&scal[3], 1u);
            atomicMax(&scal[2], fkey(m));
        }
    }
}

/* select A (candidate vs fallback); fallback per-image means reduced from
   pbsum here (was a separate kernel). */
__global__ __launch_bounds__(256) void k_selA(const unsigned* __restrict__ scal,
                                              const float* __restrict__ pbsum,
                                              float* __restrict__ fscal) {
    __shared__ double simg[BATCH];
    __shared__ double ws[4];
    int t = threadIdx.x;
    int lane = t & 63, wv = t >> 6;
    for (int img = 0; img < BATCH; img++) {
        const float* p = pbsum + img * HH;
        double s = (double)p[t] + (double)p[t + 256] + (double)p[t + 512];
#pragma unroll
        for (int d = 32; d >= 1; d >>= 1) s += __shfl_down(s, (unsigned)d, 64);
        if (lane == 0) ws[wv] = s;
        __syncthreads();
        if (t == 0) simg[img] = ws[0] + ws[1] + ws[2] + ws[3];
        __syncthreads();
    }
    if (t == 0) {
        float A;
        if (scal[3]) {
            A = funkey(scal[2]);
        } else {
            double best = -1e300;
            for (int b = 0; b < BATCH; b++) {
                double m = simg[b] / (double)HW;
                if (m > best) best = m;
            }
            A = (float)best;
        }
        fscal[5] = A;
    }
}

/* final recovery, 4 pixels per thread */
__global__ __launch_bounds__(256) void k_final(const float* __restrict__ x,
                                               const float* __restrict__ V1,
                                               const float* __restrict__ fscal,
                                               float* __restrict__ out) {
    float A = fscal[5];
    float invA = 1.0f / A;
    int i = (blockIdx.x * 256 + threadIdx.x) * 4;  /* 0..NPIX-4 */
    int b = i / HW;
    int pix = i - b * HW;
    float4 v1 = *(const float4*)(V1 + i);
    float4 v1c, den;
    v1c.x = fminf(v1.x * 0.95f, 0.8f); den.x = 1.0f / (1.0f - v1c.x * invA);
    v1c.y = fminf(v1.y * 0.95f, 0.8f); den.y = 1.0f / (1.0f - v1c.y * invA);
    v1c.z = fminf(v1.z * 0.95f, 0.8f); den.z = 1.0f / (1.0f - v1c.z * invA);
    v1c.w = fminf(v1.w * 0.95f, 0.8f); den.w = 1.0f / (1.0f - v1c.w * invA);
    size_t o = (size_t)b * 3 * HW + pix;
#pragma unroll
    for (int c = 0; c < 3; c++) {
        float4 m = *(const float4*)(x + o);
        float4 y;
        y.x = fminf(fmaxf((m.x * 255.0f - v1c.x) * den.x, 0.0f), 1.0f);
        y.y = fminf(fmaxf((m.y * 255.0f - v1c.y) * den.y, 0.0f), 1.0f);
        y.z = fminf(fmaxf((m.z * 255.0f - v1c.z) * den.z, 0.0f), 1.0f);
        y.w = fminf(fmaxf((m.w * 255.0f - v1c.w) * den.w, 0.0f), 1.0f);
        *(float4*)(out + o) = y;
        o += HW;
    }
}

/* ---------------- launch ---------------- */

extern "C" void kernel_launch(void* const* d_in, const int* in_sizes, int n_in,
                              void* d_out, int out_size, void* d_ws, size_t ws_size,
                              hipStream_t stream) {
    const float* x = (const float*)d_in[0];
    float* out = (float*)d_out;

    unsigned* scal = (unsigned*)d_ws;                     /* [0]=minKey [1]=maxKey [2]=acandKey [3]=any */
    float* fscal = (float*)d_ws;                          /* [4]=thresh [5]=A */
    unsigned* hist = (unsigned*)((char*)d_ws + 96);       /* [2000] */
    float* pbsum = (float*)((char*)d_ws + 8192);          /* [6144] block partials */
    float* bmin  = (float*)((char*)d_ws + 32768);         /* [512] */
    float* bmax  = (float*)((char*)d_ws + 57344);         /* [512] */
    float* planes = (float*)((char*)d_ws + 131072);
    float* P0 = planes + (size_t)0 * NPIX;  /* V1raw (I) */
    float* P1 = planes + (size_t)1 * NPIX;  /* mmean */
    float* P2 = planes + (size_t)2 * NPIX;  /* hmin; later HAB (with P3) */
    float* P3 = planes + (size_t)3 * NPIX;  /* p */
    float* P6 = planes + (size_t)6 * NPIX;  /* V1 */
    float4* F4 = (float4*)(planes + (size_t)4 * NPIX);    /* vertical field sums, P4..P7 */
    float2* HAB = (float2*)P2;                            /* ha,hb interleaved, P2..P3 */

    k_init<<<1, 256, 0, stream>>>(scal, hist);
    k_prep<<<NROWS, 256, 0, stream>>>(x, P0, P1, P2, pbsum);
    k_minv<<<BATCH * NCHM * WW / 256, 256, 0, stream>>>(P2, P3);
    k_kv1<<<NVB, 128, 0, stream>>>(P0, P3, F4);
    k_kh1<<<NROWS, 256, 0, stream>>>(F4, HAB);
    k_kv2<<<NVB, 128, 0, stream>>>(HAB, P0, P6, bmin, bmax);
    k_mm<<<1, 256, 0, stream>>>(bmin, bmax, scal);
    k_hist<<<1024, 256, 0, stream>>>(P6, scal, hist);
    k_thresh<<<1, 256, 0, stream>>>(hist, fscal);
    k_amax<<<1024, 256, 0, stream>>>(P6, P1, fscal, scal);
    k_selA<<<1, 256, 0, stream>>>(scal, pbsum, fscal);
    k_final<<<NPIX / 1024, 256, 0, stream>>>(x, P6, fscal, out);
}

// Round 12
// 239.096 us; speedup vs baseline: 1.1241x; 1.1241x over previous
//
#include <hip/hip_runtime.h>

#define BATCH 8
#define HH 768
#define WW 1024
#define HW (HH*WW)
#define NPIX (BATCH*HW)            /* 6291456 */
#define RG 81
#define KG (2*RG+1)                /* 163 */
#define INVK2 (1.0f/((float)KG*(float)KG))
#define RM 7
#define EPSF 1e-3f
#define NBINS 2000
#define NEG_BIG_F (-1.0e30f)
#define NROWS (BATCH*HH)           /* 6144 row-blocks */

#define BH 48                      /* band height for row-major vertical passes */
#define NBAND (HH/BH)              /* 16 bands */
#define NVB 512                    /* 8 img x 16 bands x 4 col-quarters */
#define CHM 32
#define NCHM (HH/CHM)              /* 24 chunks for vertical min filter */

/* ---------------- helpers ---------------- */

__device__ inline unsigned fkey(float f) {
    unsigned u = __float_as_uint(f);
    return (u & 0x80000000u) ? ~u : (u | 0x80000000u);
}
__device__ inline float funkey(unsigned k) {
    unsigned u = (k & 0x80000000u) ? (k & 0x7fffffffu) : ~k;
    return __uint_as_float(u);
}

/* band decode for vertical passes: XCD (blockIdx%8) owns image (blockIdx%8);
   256 threads x 1 col = 256-col quarter; 16 bands of 48 rows. */
__device__ inline void bandDecode(int idx, int& img, int& c, int& h0) {
    img = idx & 7;
    int j = idx >> 3;          /* 0..63 */
    int colq = j >> 4;         /* 0..3 */
    int band = j & 15;         /* 0..15 */
    c = colq * 256 + threadIdx.x;
    h0 = band * BH;
}

__device__ inline float waveInclScan(float x) {
    int lane = threadIdx.x & 63;
#pragma unroll
    for (int d = 1; d < 64; d <<= 1) {
        float u = __shfl_up(x, (unsigned)d, 64);
        if (lane >= d) x += u;
    }
    return x;
}

/* inclusive prefix over 1024 row elements (4 per thread), result into cum[0..1023] */
__device__ inline void scanRow(float v0, float v1, float v2, float v3,
                               float* cum, float* wsum) {
    int tid = threadIdx.x;
    float c0 = v0, c1 = c0 + v1, c2 = c1 + v2, c3 = c2 + v3;
    float inc = waveInclScan(c3);
    int lane = tid & 63, wv = tid >> 6;
    if (lane == 63) wsum[wv] = inc;
    __syncthreads();
    float basev = 0.f;
    if (wv > 0) basev += wsum[0];
    if (wv > 1) basev += wsum[1];
    if (wv > 2) basev += wsum[2];
    float ex = basev + inc - c3;
    cum[4 * tid + 0] = ex + c0;
    cum[4 * tid + 1] = ex + c1;
    cum[4 * tid + 2] = ex + c2;
    cum[4 * tid + 3] = ex + c3;
}

/* ---------------- kernels ---------------- */

__global__ void k_init(unsigned* scal, unsigned* hist) {
    int t = threadIdx.x;
    for (int i = t; i < NBINS; i += 256) hist[i] = 0u;
    if (t == 0) {
        scal[0] = 0xFFFFFFFFu;  /* minKey */
        scal[1] = 0u;           /* maxKey */
        scal[2] = 0u;           /* A-cand key */
        scal[3] = 0u;           /* any flag */
    }
}

/* dark channel + channel mean + per-block partial sums + fused horizontal
   min filter (block == one image row). */
__global__ __launch_bounds__(256) void k_prep(const float* __restrict__ x,
                                              float* __restrict__ V1raw,
                                              float* __restrict__ mmean,
                                              float* __restrict__ hmin,
                                              float* __restrict__ pbsum) {
    int img = blockIdx.x / HH;
    int row = blockIdx.x % HH;
    int pix = row * WW + threadIdx.x * 4;
    size_t base = (size_t)img * 3 * HW + pix;
    float4 c0 = *(const float4*)(x + base);
    float4 c1 = *(const float4*)(x + base + HW);
    float4 c2 = *(const float4*)(x + base + 2 * (size_t)HW);
    float4 mnv, mev;
    {
        float a0 = c0.x * 255.0f, a1 = c1.x * 255.0f, a2 = c2.x * 255.0f;
        mnv.x = fminf(a0, fminf(a1, a2)); mev.x = (a0 + a1 + a2) * (1.0f / 3.0f);
        a0 = c0.y * 255.0f; a1 = c1.y * 255.0f; a2 = c2.y * 255.0f;
        mnv.y = fminf(a0, fminf(a1, a2)); mev.y = (a0 + a1 + a2) * (1.0f / 3.0f);
        a0 = c0.z * 255.0f; a1 = c1.z * 255.0f; a2 = c2.z * 255.0f;
        mnv.z = fminf(a0, fminf(a1, a2)); mev.z = (a0 + a1 + a2) * (1.0f / 3.0f);
        a0 = c0.w * 255.0f; a1 = c1.w * 255.0f; a2 = c2.w * 255.0f;
        mnv.w = fminf(a0, fminf(a1, a2)); mev.w = (a0 + a1 + a2) * (1.0f / 3.0f);
    }
    size_t po = (size_t)img * HW + pix;
    *(float4*)(V1raw + po) = mnv;
    *(float4*)(mmean + po) = mev;

    __shared__ float r[WW];
    int t = threadIdx.x;
    r[4 * t + 0] = mnv.x; r[4 * t + 1] = mnv.y; r[4 * t + 2] = mnv.z; r[4 * t + 3] = mnv.w;

    float s = mev.x + mev.y + mev.z + mev.w;
#pragma unroll
    for (int d = 32; d >= 1; d >>= 1) s += __shfl_down(s, (unsigned)d, 64);
    __shared__ float wsum[4];
    int lane = t & 63, wv = t >> 6;
    if (lane == 0) wsum[wv] = s;
    __syncthreads();
    if (t == 0)
        pbsum[blockIdx.x] = wsum[0] + wsum[1] + wsum[2] + wsum[3];

    /* horizontal min cascade (r=7) */
    float v[18];
#pragma unroll
    for (int i = 0; i < 18; i++) {
        int w = 4 * t - RM + i;
        w = w < 0 ? 0 : (w > WW - 1 ? WW - 1 : w);
        v[i] = r[w];
    }
#pragma unroll
    for (int i = 0; i < 17; i++) v[i] = fminf(v[i], v[i + 1]);   /* w2 */
#pragma unroll
    for (int i = 0; i < 15; i++) v[i] = fminf(v[i], v[i + 2]);   /* w4 */
#pragma unroll
    for (int i = 0; i < 11; i++) v[i] = fminf(v[i], v[i + 4]);   /* w8 */
    float4 o;
    o.x = fminf(v[0], v[7]);
    o.y = fminf(v[1], v[8]);
    o.z = fminf(v[2], v[9]);
    o.w = fminf(v[3], v[10]);
    *(float4*)(hmin + po) = o;
}

/* vertical min filter (r=7), thread per (col, 32-row chunk), log-cascade */
__global__ __launch_bounds__(256) void k_minv(const float* __restrict__ in,
                                              float* __restrict__ out) {
    int g = blockIdx.x * 256 + threadIdx.x;
    int w = g & (WW - 1);
    int t = g >> 10;
    int b = t / NCHM;
    int ch = t - b * NCHM;
    int h0 = ch * CHM;
    const float* col = in + (size_t)b * HW + w;
    float* ocol = out + (size_t)b * HW + w;
    float v[CHM + 14];
#pragma unroll
    for (int i = 0; i < CHM + 14; i++) {
        int h = h0 - RM + i;
        h = h < 0 ? 0 : (h > HH - 1 ? HH - 1 : h);
        v[i] = col[(size_t)h * WW];
    }
#pragma unroll
    for (int i = 0; i < CHM + 13; i++) v[i] = fminf(v[i], v[i + 1]);   /* w2 */
#pragma unroll
    for (int i = 0; i < CHM + 11; i++) v[i] = fminf(v[i], v[i + 2]);   /* w4 */
#pragma unroll
    for (int i = 0; i < CHM + 7; i++)  v[i] = fminf(v[i], v[i + 4]);   /* w8 */
#pragma unroll
    for (int i = 0; i < CHM; i++)
        ocol[(size_t)(h0 + i) * WW] = fminf(v[i], v[i + 7]);           /* w15 */
}

/* GF vertical pass 1, row-major bands: running column sums of I, p, I*p, I*I.
   Block = 48-row band x 256 cols; thread owns 1 column; all global accesses
   are contiguous row segments. OOB add/sub rows are zero-masked. */
__global__ __launch_bounds__(256) void k_kv1(const float* __restrict__ I,
                                             const float* __restrict__ p,
                                             float4* __restrict__ F4) {
    int img, c, h0;
    bandDecode(blockIdx.x, img, c, h0);
    const float* bI = I + (size_t)img * HW + c;
    const float* bP = p + (size_t)img * HW + c;
    float4* bO = F4 + (size_t)img * HW + c;

    float4 A = {0,0,0,0};   /* {sI,sP,sIp,sII} */
    int jlo = h0 - RG; if (jlo < 0) jlo = 0;
    int jhi = h0 + RG - 1; if (jhi > HH - 1) jhi = HH - 1;
    {
        float Li[8], Lp[8];
        int j = jlo;
        for (; j + 7 <= jhi; j += 8) {
#pragma unroll
            for (int k = 0; k < 8; k++) {
                Li[k] = bI[(size_t)(j + k) * WW];
                Lp[k] = bP[(size_t)(j + k) * WW];
            }
#pragma unroll
            for (int k = 0; k < 8; k++) {
                A.x += Li[k]; A.y += Lp[k]; A.z += Li[k] * Lp[k]; A.w += Li[k] * Li[k];
            }
        }
        for (; j <= jhi; j++) {
            float a = bI[(size_t)j * WW], q = bP[(size_t)j * WW];
            A.x += a; A.y += q; A.z += a * q; A.w += a * a;
        }
    }

    float Ai[8], Ap[8], Si[8], Sp[8];
    for (int h = h0; h < h0 + BH; h += 8) {
#pragma unroll
        for (int k = 0; k < 8; k++) {
            int ra = h + k + RG;
            int ca = ra <= HH - 1 ? ra : HH - 1;
            float a = bI[(size_t)ca * WW];
            float q = bP[(size_t)ca * WW];
            if (ra > HH - 1) { a = 0.f; q = 0.f; }
            Ai[k] = a; Ap[k] = q;
        }
#pragma unroll
        for (int k = 0; k < 8; k++) {
            int rs = h + k - RG;
            int cs = rs >= 0 ? rs : 0;
            float a = bI[(size_t)cs * WW];
            float q = bP[(size_t)cs * WW];
            if (rs < 0) { a = 0.f; q = 0.f; }
            Si[k] = a; Sp[k] = q;
        }
#pragma unroll
        for (int k = 0; k < 8; k++) {
            A.x += Ai[k]; A.y += Ap[k]; A.z += Ai[k] * Ap[k]; A.w += Ai[k] * Ai[k];
            bO[(size_t)(h + k) * WW] = A;
            A.x -= Si[k]; A.y -= Sp[k]; A.z -= Si[k] * Sp[k]; A.w -= Si[k] * Si[k];
        }
    }
}

/* GF horizontal pass: complete box1 sums via row scans -> a,b; then fuse
   box2's horizontal window: row scans of a,b -> windowed sums ha,hb. */
__global__ __launch_bounds__(256) void k_kh1(const float4* __restrict__ F4,
                                             float2* __restrict__ HAB) {
    __shared__ float cI[WW], cP[WW], cIp[WW], cII[WW];
    __shared__ float cA[WW], cB[WW];
    __shared__ float w0[4], w1[4], w2[4], w3[4], w4[4], w5[4];
    size_t base = (size_t)blockIdx.x * WW;
    int t = threadIdx.x;
    float4 q0 = F4[base + 4 * t + 0];
    float4 q1 = F4[base + 4 * t + 1];
    float4 q2 = F4[base + 4 * t + 2];
    float4 q3 = F4[base + 4 * t + 3];
    scanRow(q0.x, q1.x, q2.x, q3.x, cI, w0);
    scanRow(q0.y, q1.y, q2.y, q3.y, cP, w1);
    scanRow(q0.z, q1.z, q2.z, q3.z, cIp, w2);
    scanRow(q0.w, q1.w, q2.w, q3.w, cII, w3);
    __syncthreads();
    float av[4], bv[4];
#pragma unroll
    for (int j = 0; j < 4; j++) {
        int w = 4 * t + j;
        int hi = w + RG; if (hi > WW - 1) hi = WW - 1;
        int lo = w - RG - 1;
        float a = cI[hi], b = cP[hi], c = cIp[hi], d = cII[hi];
        if (lo >= 0) { a -= cI[lo]; b -= cP[lo]; c -= cIp[lo]; d -= cII[lo]; }
        float mI = a * INVK2, mP = b * INVK2, mIp = c * INVK2, mII = d * INVK2;
        float aa = (mIp - mI * mP) / ((mII - mI * mI) + EPSF);
        av[j] = aa; bv[j] = mP - aa * mI;
    }
    __syncthreads();   /* all reads of cI..cII done before any reuse barriers below */
    scanRow(av[0], av[1], av[2], av[3], cA, w4);
    scanRow(bv[0], bv[1], bv[2], bv[3], cB, w5);
    __syncthreads();
    float oa[4], ob[4];
#pragma unroll
    for (int j = 0; j < 4; j++) {
        int w = 4 * t + j;
        int hi = w + RG; if (hi > WW - 1) hi = WW - 1;
        int lo = w - RG - 1;
        float a = cA[hi], b = cB[hi];
        if (lo >= 0) { a -= cA[lo]; b -= cB[lo]; }
        oa[j] = a; ob[j] = b;
    }
    ((float4*)(HAB + base))[2 * t]     = make_float4(oa[0], ob[0], oa[1], ob[1]);
    ((float4*)(HAB + base))[2 * t + 1] = make_float4(oa[2], ob[2], oa[3], ob[3]);
}

/* GF vertical pass 2, row-major bands: sliding column sums of ha,hb;
   V1 = sum_a*INVK2*I + sum_b*INVK2; per-block min/max. */
__global__ __launch_bounds__(256) void k_kv2(const float2* __restrict__ HAB,
                                             const float* __restrict__ I,
                                             float* __restrict__ V1,
                                             float* __restrict__ bmin,
                                             float* __restrict__ bmax) {
    int img, c, h0;
    bandDecode(blockIdx.x, img, c, h0);
    const float2* bC = HAB + (size_t)img * HW + c;
    const float* bI = I + (size_t)img * HW + c;
    float* bV = V1 + (size_t)img * HW + c;

    /* acc = {sa, sb} */
    float2 s0 = {0,0}, s1 = {0,0}, s2 = {0,0}, s3 = {0,0};
    int jlo = h0 - RG; if (jlo < 0) jlo = 0;
    int jhi = h0 + RG - 1; if (jhi > HH - 1) jhi = HH - 1;
    {
        float2 L[8];
        int j = jlo;
        for (; j + 7 <= jhi; j += 8) {
#pragma unroll
            for (int k = 0; k < 8; k++) L[k] = bC[(size_t)(j + k) * WW];
            s0.x += L[0].x; s0.y += L[0].y;
            s1.x += L[1].x; s1.y += L[1].y;
            s2.x += L[2].x; s2.y += L[2].y;
            s3.x += L[3].x; s3.y += L[3].y;
            s0.x += L[4].x; s0.y += L[4].y;
            s1.x += L[5].x; s1.y += L[5].y;
            s2.x += L[6].x; s2.y += L[6].y;
            s3.x += L[7].x; s3.y += L[7].y;
        }
        for (; j <= jhi; j++) {
            float2 v = bC[(size_t)j * WW];
            s0.x += v.x; s0.y += v.y;
        }
    }
    float2 acc;
    acc.x = (s0.x + s1.x) + (s2.x + s3.x);
    acc.y = (s0.y + s1.y) + (s2.y + s3.y);

    float lmn = 3.4e38f, lmx = -3.4e38f;
    float2 A[8], S[8];
    float Iv[8];
    for (int h = h0; h < h0 + BH; h += 8) {
#pragma unroll
        for (int k = 0; k < 8; k++) {
            int ra = h + k + RG;
            int ca = ra <= HH - 1 ? ra : HH - 1;
            float2 v = bC[(size_t)ca * WW];
            if (ra > HH - 1) v = make_float2(0.f, 0.f);
            A[k] = v;
        }
#pragma unroll
        for (int k = 0; k < 8; k++) {
            int rs = h + k - RG;
            int cs = rs >= 0 ? rs : 0;
            float2 v = bC[(size_t)cs * WW];
            if (rs < 0) v = make_float2(0.f, 0.f);
            S[k] = v;
        }
#pragma unroll
        for (int k = 0; k < 8; k++) Iv[k] = bI[(size_t)(h + k) * WW];
#pragma unroll
        for (int k = 0; k < 8; k++) {
            acc.x += A[k].x; acc.y += A[k].y;
            float v0 = acc.x * INVK2 * Iv[k] + acc.y * INVK2;
            bV[(size_t)(h + k) * WW] = v0;
            lmn = fminf(lmn, v0);
            lmx = fmaxf(lmx, v0);
            acc.x -= S[k].x; acc.y -= S[k].y;
        }
    }
#pragma unroll
    for (int d = 32; d >= 1; d >>= 1) {
        lmn = fminf(lmn, __shfl_down(lmn, (unsigned)d, 64));
        lmx = fmaxf(lmx, __shfl_down(lmx, (unsigned)d, 64));
    }
    __shared__ float smn[4], smx[4];
    int lane = threadIdx.x & 63, wv = threadIdx.x >> 6;
    if (lane == 0) { smn[wv] = lmn; smx[wv] = lmx; }
    __syncthreads();
    if (threadIdx.x == 0) {
        bmin[blockIdx.x] = fminf(fminf(smn[0], smn[1]), fminf(smn[2], smn[3]));
        bmax[blockIdx.x] = fmaxf(fmaxf(smx[0], smx[1]), fmaxf(smx[2], smx[3]));
    }
}

/* reduce per-block min/max -> scal keys (single block) */
__global__ __launch_bounds__(256) void k_mm(const float* __restrict__ bmin,
                                            const float* __restrict__ bmax,
                                            unsigned* __restrict__ scal) {
    float mn = 3.4e38f, mx = -3.4e38f;
    for (int i = threadIdx.x; i < NVB; i += 256) {
        mn = fminf(mn, bmin[i]);
        mx = fmaxf(mx, bmax[i]);
    }
#pragma unroll
    for (int d = 32; d >= 1; d >>= 1) {
        mn = fminf(mn, __shfl_down(mn, (unsigned)d, 64));
        mx = fmaxf(mx, __shfl_down(mx, (unsigned)d, 64));
    }
    __shared__ float smn[4], smx[4];
    int lane = threadIdx.x & 63, wv = threadIdx.x >> 6;
    if (lane == 0) { smn[wv] = mn; smx[wv] = mx; }
    __syncthreads();
    if (threadIdx.x == 0) {
        float a = fminf(fminf(smn[0], smn[1]), fminf(smn[2], smn[3]));
        float b = fmaxf(fmaxf(smx[0], smx[1]), fmaxf(smx[2], smx[3]));
        scal[0] = fkey(a);
        scal[1] = fkey(b);
    }
}

/* histogram (2000 bins over [mn,mx]), float4 reads */
__global__ __launch_bounds__(256) void k_hist(const float* __restrict__ V1,
                                              const unsigned* __restrict__ scal,
                                              unsigned* __restrict__ hist) {
    __shared__ unsigned lh[NBINS];
    for (int i = threadIdx.x; i < NBINS; i += 256) lh[i] = 0u;
    __syncthreads();
    float mn = funkey(scal[0]);
    float mx = funkey(scal[1]);
    float inv = 2000.0f / (mx - mn);
    const float4* V4 = (const float4*)V1;
    for (int i = blockIdx.x * 256 + threadIdx.x; i < NPIX / 4; i += gridDim.x * 256) {
        float4 v = V4[i];
        int i0 = (int)((v.x - mn) * inv); i0 = i0 < 0 ? 0 : (i0 > NBINS - 1 ? NBINS - 1 : i0);
        int i1 = (int)((v.y - mn) * inv); i1 = i1 < 0 ? 0 : (i1 > NBINS - 1 ? NBINS - 1 : i1);
        int i2 = (int)((v.z - mn) * inv); i2 = i2 < 0 ? 0 : (i2 > NBINS - 1 ? NBINS - 1 : i2);
        int i3 = (int)((v.w - mn) * inv); i3 = i3 < 0 ? 0 : (i3 > NBINS - 1 ? NBINS - 1 : i3);
        atomicAdd(&lh[i0], 1u);
        atomicAdd(&lh[i1], 1u);
        atomicAdd(&lh[i2], 1u);
        atomicAdd(&lh[i3], 1u);
    }
    __syncthreads();
    for (int i = threadIdx.x; i < NBINS; i += 256) {
        unsigned c = lh[i];
        if (c) atomicAdd(&hist[i], c);
    }
}

/* cumulative -> threshold (count at 99.9% bin), parallel block scan */
__global__ __launch_bounds__(256) void k_thresh(const unsigned* __restrict__ hist,
                                                float* __restrict__ fscal) {
    int t = threadIdx.x;
    unsigned h[8];
    float local = 0.f;
#pragma unroll
    for (int j = 0; j < 8; j++) {
        int idx = t * 8 + j;
        h[j] = (idx < NBINS) ? hist[idx] : 0u;
        local += (float)h[j];
    }
    float inc = waveInclScan(local);
    __shared__ float wsum[4];
    __shared__ int smax[4];
    int lane = t & 63, wv = t >> 6;
    if (lane == 63) wsum[wv] = inc;
    __syncthreads();
    float basev = 0.f;
    if (wv > 0) basev += wsum[0];
    if (wv > 1) basev += wsum[1];
    if (wv > 2) basev += wsum[2];
    float cum = basev + inc - local;   /* exclusive prefix; exact (integers < 2^24) */
    int lmax = -1;
#pragma unroll
    for (int j = 0; j < 8; j++) {
        int idx = t * 8 + j;
        cum += (float)h[j];
        float d = cum / (float)NPIX;
        if (idx < NBINS && d <= 0.999f) lmax = idx;
    }
#pragma unroll
    for (int d = 32; d >= 1; d >>= 1) {
        int o = __shfl_down(lmax, (unsigned)d, 64);
        lmax = o > lmax ? o : lmax;
    }
    if (lane == 0) smax[wv] = lmax;
    __syncthreads();
    if (t == 0) {
        int m = smax[0];
        if (smax[1] > m) m = smax[1];
        if (smax[2] > m) m = smax[2];
        if (smax[3] > m) m = smax[3];
        int idx = m < 0 ? NBINS - 1 : m;  /* hist[-1] wraps in the reference */
        fscal[4] = (float)hist[idx];
    }
}

/* masked max of channel-mean where V1 >= thresh, plus any(mask) */
__global__ __launch_bounds__(256) void k_amax(const float* __restrict__ V1,
                                              const float* __restrict__ mmean,
                                              const float* __restrict__ fscal,
                                              unsigned* __restrict__ scal) {
    float th = fscal[4];
    float lmax = NEG_BIG_F;
    bool any = false;
    const float4* V4 = (const float4*)V1;
    const float4* M4 = (const float4*)mmean;
    for (int i = blockIdx.x * 256 + threadIdx.x; i < NPIX / 4; i += gridDim.x * 256) {
        float4 v = V4[i];
        if (v.x >= th || v.y >= th || v.z >= th || v.w >= th) {
            float4 m = M4[i];
            any = true;
            if (v.x >= th) lmax = fmaxf(lmax, m.x);
            if (v.y >= th) lmax = fmaxf(lmax, m.y);
            if (v.z >= th) lmax = fmaxf(lmax, m.z);
            if (v.w >= th) lmax = fmaxf(lmax, m.w);
        }
    }
#pragma unroll
    for (int d = 32; d >= 1; d >>= 1) lmax = fmaxf(lmax, __shfl_down(lmax, (unsigned)d, 64));
    unsigned long long ab = __ballot(any);
    __shared__ float smx[4];
    __shared__ unsigned sany[4];
    int lane = threadIdx.x & 63, wv = threadIdx.x >> 6;
    if (lane == 0) { smx[wv] = lmax; sany[wv] = ab ? 1u : 0u; }
    __syncthreads();
    if (threadIdx.x == 0) {
        float m = fmaxf(fmaxf(smx[0], smx[1]), fmaxf(smx[2], smx[3]));
        unsigned a = sany[0] | sany[1] | sany[2] | sany[3];
        if (a) {
            atomicOr(&scal[3], 1u);
            atomicMax(&scal[2], fkey(m));
        }
    }
}

/* select A (candidate vs fallback); fallback per-image means reduced from
   pbsum here. */
__global__ __launch_bounds__(256) void k_selA(const unsigned* __restrict__ scal,
                                              const float* __restrict__ pbsum,
                                              float* __restrict__ fscal) {
    __shared__ double simg[BATCH];
    __shared__ double ws[4];
    int t = threadIdx.x;
    int lane = t & 63, wv = t >> 6;
    for (int img = 0; img < BATCH; img++) {
        const float* p = pbsum + img * HH;
        double s = (double)p[t] + (double)p[t + 256] + (double)p[t + 512];
#pragma unroll
        for (int d = 32; d >= 1; d >>= 1) s += __shfl_down(s, (unsigned)d, 64);
        if (lane == 0) ws[wv] = s;
        __syncthreads();
        if (t == 0) simg[img] = ws[0] + ws[1] + ws[2] + ws[3];
        __syncthreads();
    }
    if (t == 0) {
        float A;
        if (scal[3]) {
            A = funkey(scal[2]);
        } else {
            double best = -1e300;
            for (int b = 0; b < BATCH; b++) {
                double m = simg[b] / (double)HW;
                if (m > best) best = m;
            }
            A = (float)best;
        }
        fscal[5] = A;
    }
}

/* final recovery, 4 pixels per thread */
__global__ __launch_bounds__(256) void k_final(const float* __restrict__ x,
                                               const float* __restrict__ V1,
                                               const float* __restrict__ fscal,
                                               float* __restrict__ out) {
    float A = fscal[5];
    float invA = 1.0f / A;
    int i = (blockIdx.x * 256 + threadIdx.x) * 4;  /* 0..NPIX-4 */
    int b = i / HW;
    int pix = i - b * HW;
    float4 v1 = *(const float4*)(V1 + i);
    float4 v1c, den;
    v1c.x = fminf(v1.x * 0.95f, 0.8f); den.x = 1.0f / (1.0f - v1c.x * invA);
    v1c.y = fminf(v1.y * 0.95f, 0.8f); den.y = 1.0f / (1.0f - v1c.y * invA);
    v1c.z = fminf(v1.z * 0.95f, 0.8f); den.z = 1.0f / (1.0f - v1c.z * invA);
    v1c.w = fminf(v1.w * 0.95f, 0.8f); den.w = 1.0f / (1.0f - v1c.w * invA);
    size_t o = (size_t)b * 3 * HW + pix;
#pragma unroll
    for (int c = 0; c < 3; c++) {
        float4 m = *(const float4*)(x + o);
        float4 y;
        y.x = fminf(fmaxf((m.x * 255.0f - v1c.x) * den.x, 0.0f), 1.0f);
        y.y = fminf(fmaxf((m.y * 255.0f - v1c.y) * den.y, 0.0f), 1.0f);
        y.z = fminf(fmaxf((m.z * 255.0f - v1c.z) * den.z, 0.0f), 1.0f);
        y.w = fminf(fmaxf((m.w * 255.0f - v1c.w) * den.w, 0.0f), 1.0f);
        *(float4*)(out + o) = y;
        o += HW;
    }
}

/* ---------------- launch ---------------- */

extern "C" void kernel_launch(void* const* d_in, const int* in_sizes, int n_in,
                              void* d_out, int out_size, void* d_ws, size_t ws_size,
                              hipStream_t stream) {
    const float* x = (const float*)d_in[0];
    float* out = (float*)d_out;

    unsigned* scal = (unsigned*)d_ws;                     /* [0]=minKey [1]=maxKey [2]=acandKey [3]=any */
    float* fscal = (float*)d_ws;                          /* [4]=thresh [5]=A */
    unsigned* hist = (unsigned*)((char*)d_ws + 96);       /* [2000] */
    float* pbsum = (float*)((char*)d_ws + 8192);          /* [6144] block partials */
    float* bmin  = (float*)((char*)d_ws + 32768);         /* [512] */
    float* bmax  = (float*)((char*)d_ws + 57344);         /* [512] */
    float* planes = (float*)((char*)d_ws + 131072);
    float* P0 = planes + (size_t)0 * NPIX;  /* V1raw (I) */
    float* P1 = planes + (size_t)1 * NPIX;  /* mmean */
    float* P2 = planes + (size_t)2 * NPIX;  /* hmin; later HAB (with P3) */
    float* P3 = planes + (size_t)3 * NPIX;  /* p */
    float* P6 = planes + (size_t)6 * NPIX;  /* V1 */
    float4* F4 = (float4*)(planes + (size_t)4 * NPIX);    /* vertical field sums, P4..P7 */
    float2* HAB = (float2*)P2;                            /* ha,hb interleaved, P2..P3 */

    k_init<<<1, 256, 0, stream>>>(scal, hist);
    k_prep<<<NROWS, 256, 0, stream>>>(x, P0, P1, P2, pbsum);
    k_minv<<<BATCH * NCHM * WW / 256, 256, 0, stream>>>(P2, P3);
    k_kv1<<<NVB, 256, 0, stream>>>(P0, P3, F4);
    k_kh1<<<NROWS, 256, 0, stream>>>(F4, HAB);
    k_kv2<<<NVB, 256, 0, stream>>>(HAB, P0, P6, bmin, bmax);
    k_mm<<<1, 256, 0, stream>>>(bmin, bmax, scal);
    k_hist<<<1024, 256, 0, stream>>>(P6, scal, hist);
    k_thresh<<<1, 256, 0, stream>>>(hist, fscal);
    k_amax<<<1024, 256, 0, stream>>>(P6, P1, fscal, scal);
    k_selA<<<1, 256, 0, stream>>>(scal, pbsum, fscal);
    k_final<<<NPIX / 1024, 256, 0, stream>>>(x, P6, fscal, out);
}

// Round 13
// 236.560 us; speedup vs baseline: 1.1361x; 1.0107x over previous
//
#include <hip/hip_runtime.h>

#define BATCH 8
#define HH 768
#define WW 1024
#define HW (HH*WW)
#define NPIX (BATCH*HW)            /* 6291456 */
#define RG 81
#define KG (2*RG+1)                /* 163 */
#define INVK2 (1.0f/((float)KG*(float)KG))
#define RM 7
#define EPSF 1e-3f
#define NBINS 2000
#define NEG_BIG_F (-1.0e30f)
#define NROWS (BATCH*HH)           /* 6144 row-blocks */

#define BH 48                      /* band height for row-major vertical passes */
#define NVB 512                    /* 8 img x 16 bands x 4 col-quarters */
#define CHM 32
#define NCHM (HH/CHM)              /* 24 chunks for vertical min filter */

/* ---------------- helpers ---------------- */

__device__ inline unsigned fkey(float f) {
    unsigned u = __float_as_uint(f);
    return (u & 0x80000000u) ? ~u : (u | 0x80000000u);
}
__device__ inline float funkey(unsigned k) {
    unsigned u = (k & 0x80000000u) ? (k & 0x7fffffffu) : ~k;
    return __uint_as_float(u);
}

/* band decode for vertical passes: XCD (blockIdx%8) owns image (blockIdx%8);
   256 threads x 1 col = 256-col quarter; 16 bands of 48 rows. */
__device__ inline void bandDecode(int idx, int& img, int& c, int& h0) {
    img = idx & 7;
    int j = idx >> 3;          /* 0..63 */
    int colq = j >> 4;         /* 0..3 */
    int band = j & 15;         /* 0..15 */
    c = colq * 256 + threadIdx.x;
    h0 = band * BH;
}

__device__ inline float waveInclScan(float x) {
    int lane = threadIdx.x & 63;
#pragma unroll
    for (int d = 1; d < 64; d <<= 1) {
        float u = __shfl_up(x, (unsigned)d, 64);
        if (lane >= d) x += u;
    }
    return x;
}

/* inclusive prefix over 1024 row elements (4 per thread), result into cum[0..1023] */
__device__ inline void scanRow(float v0, float v1, float v2, float v3,
                               float* cum, float* wsum) {
    int tid = threadIdx.x;
    float c0 = v0, c1 = c0 + v1, c2 = c1 + v2, c3 = c2 + v3;
    float inc = waveInclScan(c3);
    int lane = tid & 63, wv = tid >> 6;
    if (lane == 63) wsum[wv] = inc;
    __syncthreads();
    float basev = 0.f;
    if (wv > 0) basev += wsum[0];
    if (wv > 1) basev += wsum[1];
    if (wv > 2) basev += wsum[2];
    float ex = basev + inc - c3;
    cum[4 * tid + 0] = ex + c0;
    cum[4 * tid + 1] = ex + c1;
    cum[4 * tid + 2] = ex + c2;
    cum[4 * tid + 3] = ex + c3;
}

/* ---------------- kernels ---------------- */

/* dark channel + channel mean + per-block partial sums + fused horizontal
   min filter (block == one image row). Block 0 also initializes hist/scal. */
__global__ __launch_bounds__(256) void k_prep(const float* __restrict__ x,
                                              float* __restrict__ V1raw,
                                              float* __restrict__ mmean,
                                              float* __restrict__ hmin,
                                              float* __restrict__ pbsum,
                                              unsigned* __restrict__ scal,
                                              unsigned* __restrict__ hist) {
    int t = threadIdx.x;
    if (blockIdx.x == 0) {
        for (int i = t; i < NBINS; i += 256) hist[i] = 0u;
        if (t == 0) {
            scal[0] = 0xFFFFFFFFu;  /* minKey */
            scal[1] = 0u;           /* maxKey */
            scal[2] = 0u;           /* A-cand key */
            scal[3] = 0u;           /* any flag */
        }
    }
    int img = blockIdx.x / HH;
    int row = blockIdx.x % HH;
    int pix = row * WW + t * 4;
    size_t base = (size_t)img * 3 * HW + pix;
    float4 c0 = *(const float4*)(x + base);
    float4 c1 = *(const float4*)(x + base + HW);
    float4 c2 = *(const float4*)(x + base + 2 * (size_t)HW);
    float4 mnv, mev;
    {
        float a0 = c0.x * 255.0f, a1 = c1.x * 255.0f, a2 = c2.x * 255.0f;
        mnv.x = fminf(a0, fminf(a1, a2)); mev.x = (a0 + a1 + a2) * (1.0f / 3.0f);
        a0 = c0.y * 255.0f; a1 = c1.y * 255.0f; a2 = c2.y * 255.0f;
        mnv.y = fminf(a0, fminf(a1, a2)); mev.y = (a0 + a1 + a2) * (1.0f / 3.0f);
        a0 = c0.z * 255.0f; a1 = c1.z * 255.0f; a2 = c2.z * 255.0f;
        mnv.z = fminf(a0, fminf(a1, a2)); mev.z = (a0 + a1 + a2) * (1.0f / 3.0f);
        a0 = c0.w * 255.0f; a1 = c1.w * 255.0f; a2 = c2.w * 255.0f;
        mnv.w = fminf(a0, fminf(a1, a2)); mev.w = (a0 + a1 + a2) * (1.0f / 3.0f);
    }
    size_t po = (size_t)img * HW + pix;
    *(float4*)(V1raw + po) = mnv;
    *(float4*)(mmean + po) = mev;

    __shared__ float r[WW];
    r[4 * t + 0] = mnv.x; r[4 * t + 1] = mnv.y; r[4 * t + 2] = mnv.z; r[4 * t + 3] = mnv.w;

    float s = mev.x + mev.y + mev.z + mev.w;
#pragma unroll
    for (int d = 32; d >= 1; d >>= 1) s += __shfl_down(s, (unsigned)d, 64);
    __shared__ float wsum[4];
    int lane = t & 63, wv = t >> 6;
    if (lane == 0) wsum[wv] = s;
    __syncthreads();
    if (t == 0)
        pbsum[blockIdx.x] = wsum[0] + wsum[1] + wsum[2] + wsum[3];

    /* horizontal min cascade (r=7) */
    float v[18];
#pragma unroll
    for (int i = 0; i < 18; i++) {
        int w = 4 * t - RM + i;
        w = w < 0 ? 0 : (w > WW - 1 ? WW - 1 : w);
        v[i] = r[w];
    }
#pragma unroll
    for (int i = 0; i < 17; i++) v[i] = fminf(v[i], v[i + 1]);   /* w2 */
#pragma unroll
    for (int i = 0; i < 15; i++) v[i] = fminf(v[i], v[i + 2]);   /* w4 */
#pragma unroll
    for (int i = 0; i < 11; i++) v[i] = fminf(v[i], v[i + 4]);   /* w8 */
    float4 o;
    o.x = fminf(v[0], v[7]);
    o.y = fminf(v[1], v[8]);
    o.z = fminf(v[2], v[9]);
    o.w = fminf(v[3], v[10]);
    *(float4*)(hmin + po) = o;
}

/* vertical min filter (r=7), thread per (col, 32-row chunk), log-cascade */
__global__ __launch_bounds__(256) void k_minv(const float* __restrict__ in,
                                              float* __restrict__ out) {
    int g = blockIdx.x * 256 + threadIdx.x;
    int w = g & (WW - 1);
    int t = g >> 10;
    int b = t / NCHM;
    int ch = t - b * NCHM;
    int h0 = ch * CHM;
    const float* col = in + (size_t)b * HW + w;
    float* ocol = out + (size_t)b * HW + w;
    float v[CHM + 14];
#pragma unroll
    for (int i = 0; i < CHM + 14; i++) {
        int h = h0 - RM + i;
        h = h < 0 ? 0 : (h > HH - 1 ? HH - 1 : h);
        v[i] = col[(size_t)h * WW];
    }
#pragma unroll
    for (int i = 0; i < CHM + 13; i++) v[i] = fminf(v[i], v[i + 1]);   /* w2 */
#pragma unroll
    for (int i = 0; i < CHM + 11; i++) v[i] = fminf(v[i], v[i + 2]);   /* w4 */
#pragma unroll
    for (int i = 0; i < CHM + 7; i++)  v[i] = fminf(v[i], v[i + 4]);   /* w8 */
#pragma unroll
    for (int i = 0; i < CHM; i++)
        ocol[(size_t)(h0 + i) * WW] = fminf(v[i], v[i + 7]);           /* w15 */
}

/* GF vertical pass 1, row-major bands: running column sums of I, p, I*p, I*I.
   Block = 48-row band x 256 cols; thread owns 1 column; all global accesses
   are contiguous row segments. OOB add/sub rows are zero-masked. */
__global__ __launch_bounds__(256) void k_kv1(const float* __restrict__ I,
                                             const float* __restrict__ p,
                                             float4* __restrict__ F4) {
    int img, c, h0;
    bandDecode(blockIdx.x, img, c, h0);
    const float* bI = I + (size_t)img * HW + c;
    const float* bP = p + (size_t)img * HW + c;
    float4* bO = F4 + (size_t)img * HW + c;

    float4 A = {0,0,0,0};   /* {sI,sP,sIp,sII} */
    int jlo = h0 - RG; if (jlo < 0) jlo = 0;
    int jhi = h0 + RG - 1; if (jhi > HH - 1) jhi = HH - 1;
    {
        float Li[8], Lp[8];
        int j = jlo;
        for (; j + 7 <= jhi; j += 8) {
#pragma unroll
            for (int k = 0; k < 8; k++) {
                Li[k] = bI[(size_t)(j + k) * WW];
                Lp[k] = bP[(size_t)(j + k) * WW];
            }
#pragma unroll
            for (int k = 0; k < 8; k++) {
                A.x += Li[k]; A.y += Lp[k]; A.z += Li[k] * Lp[k]; A.w += Li[k] * Li[k];
            }
        }
        for (; j <= jhi; j++) {
            float a = bI[(size_t)j * WW], q = bP[(size_t)j * WW];
            A.x += a; A.y += q; A.z += a * q; A.w += a * a;
        }
    }

    float Ai[8], Ap[8], Si[8], Sp[8];
    for (int h = h0; h < h0 + BH; h += 8) {
#pragma unroll
        for (int k = 0; k < 8; k++) {
            int ra = h + k + RG;
            int ca = ra <= HH - 1 ? ra : HH - 1;
            float a = bI[(size_t)ca * WW];
            float q = bP[(size_t)ca * WW];
            if (ra > HH - 1) { a = 0.f; q = 0.f; }
            Ai[k] = a; Ap[k] = q;
        }
#pragma unroll
        for (int k = 0; k < 8; k++) {
            int rs = h + k - RG;
            int cs = rs >= 0 ? rs : 0;
            float a = bI[(size_t)cs * WW];
            float q = bP[(size_t)cs * WW];
            if (rs < 0) { a = 0.f; q = 0.f; }
            Si[k] = a; Sp[k] = q;
        }
#pragma unroll
        for (int k = 0; k < 8; k++) {
            A.x += Ai[k]; A.y += Ap[k]; A.z += Ai[k] * Ap[k]; A.w += Ai[k] * Ai[k];
            bO[(size_t)(h + k) * WW] = A;
            A.x -= Si[k]; A.y -= Sp[k]; A.z -= Si[k] * Sp[k]; A.w -= Si[k] * Si[k];
        }
    }
}

/* GF horizontal pass: complete box1 sums via row scans -> a,b; then fuse
   box2's horizontal window: row scans of a,b -> windowed sums ha,hb. */
__global__ __launch_bounds__(256) void k_kh1(const float4* __restrict__ F4,
                                             float2* __restrict__ HAB) {
    __shared__ float cI[WW], cP[WW], cIp[WW], cII[WW];
    __shared__ float cA[WW], cB[WW];
    __shared__ float w0[4], w1[4], w2[4], w3[4], w4[4], w5[4];
    size_t base = (size_t)blockIdx.x * WW;
    int t = threadIdx.x;
    float4 q0 = F4[base + 4 * t + 0];
    float4 q1 = F4[base + 4 * t + 1];
    float4 q2 = F4[base + 4 * t + 2];
    float4 q3 = F4[base + 4 * t + 3];
    scanRow(q0.x, q1.x, q2.x, q3.x, cI, w0);
    scanRow(q0.y, q1.y, q2.y, q3.y, cP, w1);
    scanRow(q0.z, q1.z, q2.z, q3.z, cIp, w2);
    scanRow(q0.w, q1.w, q2.w, q3.w, cII, w3);
    __syncthreads();
    float av[4], bv[4];
#pragma unroll
    for (int j = 0; j < 4; j++) {
        int w = 4 * t + j;
        int hi = w + RG; if (hi > WW - 1) hi = WW - 1;
        int lo = w - RG - 1;
        float a = cI[hi], b = cP[hi], c = cIp[hi], d = cII[hi];
        if (lo >= 0) { a -= cI[lo]; b -= cP[lo]; c -= cIp[lo]; d -= cII[lo]; }
        float mI = a * INVK2, mP = b * INVK2, mIp = c * INVK2, mII = d * INVK2;
        float aa = (mIp - mI * mP) / ((mII - mI * mI) + EPSF);
        av[j] = aa; bv[j] = mP - aa * mI;
    }
    __syncthreads();   /* all reads of cI..cII done before any reuse barriers below */
    scanRow(av[0], av[1], av[2], av[3], cA, w4);
    scanRow(bv[0], bv[1], bv[2], bv[3], cB, w5);
    __syncthreads();
    float oa[4], ob[4];
#pragma unroll
    for (int j = 0; j < 4; j++) {
        int w = 4 * t + j;
        int hi = w + RG; if (hi > WW - 1) hi = WW - 1;
        int lo = w - RG - 1;
        float a = cA[hi], b = cB[hi];
        if (lo >= 0) { a -= cA[lo]; b -= cB[lo]; }
        oa[j] = a; ob[j] = b;
    }
    ((float4*)(HAB + base))[2 * t]     = make_float4(oa[0], ob[0], oa[1], ob[1]);
    ((float4*)(HAB + base))[2 * t + 1] = make_float4(oa[2], ob[2], oa[3], ob[3]);
}

/* GF vertical pass 2, row-major bands: sliding column sums of ha,hb;
   V1 = sum_a*INVK2*I + sum_b*INVK2; block min/max -> device atomics. */
__global__ __launch_bounds__(256) void k_kv2(const float2* __restrict__ HAB,
                                             const float* __restrict__ I,
                                             float* __restrict__ V1,
                                             unsigned* __restrict__ scal) {
    int img, c, h0;
    bandDecode(blockIdx.x, img, c, h0);
    const float2* bC = HAB + (size_t)img * HW + c;
    const float* bI = I + (size_t)img * HW + c;
    float* bV = V1 + (size_t)img * HW + c;

    /* acc = {sa, sb} */
    float2 s0 = {0,0}, s1 = {0,0}, s2 = {0,0}, s3 = {0,0};
    int jlo = h0 - RG; if (jlo < 0) jlo = 0;
    int jhi = h0 + RG - 1; if (jhi > HH - 1) jhi = HH - 1;
    {
        float2 L[8];
        int j = jlo;
        for (; j + 7 <= jhi; j += 8) {
#pragma unroll
            for (int k = 0; k < 8; k++) L[k] = bC[(size_t)(j + k) * WW];
            s0.x += L[0].x; s0.y += L[0].y;
            s1.x += L[1].x; s1.y += L[1].y;
            s2.x += L[2].x; s2.y += L[2].y;
            s3.x += L[3].x; s3.y += L[3].y;
            s0.x += L[4].x; s0.y += L[4].y;
            s1.x += L[5].x; s1.y += L[5].y;
            s2.x += L[6].x; s2.y += L[6].y;
            s3.x += L[7].x; s3.y += L[7].y;
        }
        for (; j <= jhi; j++) {
            float2 v = bC[(size_t)j * WW];
            s0.x += v.x; s0.y += v.y;
        }
    }
    float2 acc;
    acc.x = (s0.x + s1.x) + (s2.x + s3.x);
    acc.y = (s0.y + s1.y) + (s2.y + s3.y);

    float lmn = 3.4e38f, lmx = -3.4e38f;
    float2 A[8], S[8];
    float Iv[8];
    for (int h = h0; h < h0 + BH; h += 8) {
#pragma unroll
        for (int k = 0; k < 8; k++) {
            int ra = h + k + RG;
            int ca = ra <= HH - 1 ? ra : HH - 1;
            float2 v = bC[(size_t)ca * WW];
            if (ra > HH - 1) v = make_float2(0.f, 0.f);
            A[k] = v;
        }
#pragma unroll
        for (int k = 0; k < 8; k++) {
            int rs = h + k - RG;
            int cs = rs >= 0 ? rs : 0;
            float2 v = bC[(size_t)cs * WW];
            if (rs < 0) v = make_float2(0.f, 0.f);
            S[k] = v;
        }
#pragma unroll
        for (int k = 0; k < 8; k++) Iv[k] = bI[(size_t)(h + k) * WW];
#pragma unroll
        for (int k = 0; k < 8; k++) {
            acc.x += A[k].x; acc.y += A[k].y;
            float v0 = acc.x * INVK2 * Iv[k] + acc.y * INVK2;
            bV[(size_t)(h + k) * WW] = v0;
            lmn = fminf(lmn, v0);
            lmx = fmaxf(lmx, v0);
            acc.x -= S[k].x; acc.y -= S[k].y;
        }
    }
#pragma unroll
    for (int d = 32; d >= 1; d >>= 1) {
        lmn = fminf(lmn, __shfl_down(lmn, (unsigned)d, 64));
        lmx = fmaxf(lmx, __shfl_down(lmx, (unsigned)d, 64));
    }
    __shared__ float smn[4], smx[4];
    int lane = threadIdx.x & 63, wv = threadIdx.x >> 6;
    if (lane == 0) { smn[wv] = lmn; smx[wv] = lmx; }
    __syncthreads();
    if (threadIdx.x == 0) {
        float a = fminf(fminf(smn[0], smn[1]), fminf(smn[2], smn[3]));
        float b = fmaxf(fmaxf(smx[0], smx[1]), fmaxf(smx[2], smx[3]));
        atomicMin(&scal[0], fkey(a));
        atomicMax(&scal[1], fkey(b));
    }
}

/* histogram (2000 bins over [mn,mx]), float4 reads */
__global__ __launch_bounds__(256) void k_hist(const float* __restrict__ V1,
                                              const unsigned* __restrict__ scal,
                                              unsigned* __restrict__ hist) {
    __shared__ unsigned lh[NBINS];
    for (int i = threadIdx.x; i < NBINS; i += 256) lh[i] = 0u;
    __syncthreads();
    float mn = funkey(scal[0]);
    float mx = funkey(scal[1]);
    float inv = 2000.0f / (mx - mn);
    const float4* V4 = (const float4*)V1;
    for (int i = blockIdx.x * 256 + threadIdx.x; i < NPIX / 4; i += gridDim.x * 256) {
        float4 v = V4[i];
        int i0 = (int)((v.x - mn) * inv); i0 = i0 < 0 ? 0 : (i0 > NBINS - 1 ? NBINS - 1 : i0);
        int i1 = (int)((v.y - mn) * inv); i1 = i1 < 0 ? 0 : (i1 > NBINS - 1 ? NBINS - 1 : i1);
        int i2 = (int)((v.z - mn) * inv); i2 = i2 < 0 ? 0 : (i2 > NBINS - 1 ? NBINS - 1 : i2);
        int i3 = (int)((v.w - mn) * inv); i3 = i3 < 0 ? 0 : (i3 > NBINS - 1 ? NBINS - 1 : i3);
        atomicAdd(&lh[i0], 1u);
        atomicAdd(&lh[i1], 1u);
        atomicAdd(&lh[i2], 1u);
        atomicAdd(&lh[i3], 1u);
    }
    __syncthreads();
    for (int i = threadIdx.x; i < NBINS; i += 256) {
        unsigned c = lh[i];
        if (c) atomicAdd(&hist[i], c);
    }
}

/* masked max of channel-mean where V1 >= thresh, plus any(mask).
   Threshold (count at 99.9% bin) computed inline per block from hist. */
__global__ __launch_bounds__(256) void k_amax(const float* __restrict__ V1,
                                              const float* __restrict__ mmean,
                                              const unsigned* __restrict__ hist,
                                              unsigned* __restrict__ scal) {
    __shared__ float wsum[4];
    __shared__ int smaxi[4];
    __shared__ float sthresh;
    int t = threadIdx.x;
    int lane = t & 63, wv = t >> 6;
    {
        unsigned h[8];
        float local = 0.f;
#pragma unroll
        for (int j = 0; j < 8; j++) {
            int idx = t * 8 + j;
            h[j] = (idx < NBINS) ? hist[idx] : 0u;
            local += (float)h[j];
        }
        float inc = waveInclScan(local);
        if (lane == 63) wsum[wv] = inc;
        __syncthreads();
        float basev = 0.f;
        if (wv > 0) basev += wsum[0];
        if (wv > 1) basev += wsum[1];
        if (wv > 2) basev += wsum[2];
        float cum = basev + inc - local;   /* exclusive prefix; exact (ints < 2^24) */
        int lmax = -1;
#pragma unroll
        for (int j = 0; j < 8; j++) {
            int idx = t * 8 + j;
            cum += (float)h[j];
            float d = cum / (float)NPIX;
            if (idx < NBINS && d <= 0.999f) lmax = idx;
        }
#pragma unroll
        for (int d = 32; d >= 1; d >>= 1) {
            int o = __shfl_down(lmax, (unsigned)d, 64);
            lmax = o > lmax ? o : lmax;
        }
        if (lane == 0) smaxi[wv] = lmax;
        __syncthreads();
        if (t == 0) {
            int m = smaxi[0];
            if (smaxi[1] > m) m = smaxi[1];
            if (smaxi[2] > m) m = smaxi[2];
            if (smaxi[3] > m) m = smaxi[3];
            int idx = m < 0 ? NBINS - 1 : m;  /* hist[-1] wraps in the reference */
            sthresh = (float)hist[idx];
        }
        __syncthreads();
    }
    float th = sthresh;

    float lmax = NEG_BIG_F;
    bool any = false;
    const float4* V4 = (const float4*)V1;
    const float4* M4 = (const float4*)mmean;
    for (int i = blockIdx.x * 256 + t; i < NPIX / 4; i += gridDim.x * 256) {
        float4 v = V4[i];
        if (v.x >= th || v.y >= th || v.z >= th || v.w >= th) {
            float4 m = M4[i];
            any = true;
            if (v.x >= th) lmax = fmaxf(lmax, m.x);
            if (v.y >= th) lmax = fmaxf(lmax, m.y);
            if (v.z >= th) lmax = fmaxf(lmax, m.z);
            if (v.w >= th) lmax = fmaxf(lmax, m.w);
        }
    }
#pragma unroll
    for (int d = 32; d >= 1; d >>= 1) lmax = fmaxf(lmax, __shfl_down(lmax, (unsigned)d, 64));
    unsigned long long ab = __ballot(any);
    __shared__ float smx[4];
    __shared__ unsigned sany[4];
    if (lane == 0) { smx[wv] = lmax; sany[wv] = ab ? 1u : 0u; }
    __syncthreads();
    if (t == 0) {
        float m = fmaxf(fmaxf(smx[0], smx[1]), fmaxf(smx[2], smx[3]));
        unsigned a = sany[0] | sany[1] | sany[2] | sany[3];
        if (a) {
            atomicOr(&scal[3], 1u);
            atomicMax(&scal[2], fkey(m));
        }
    }
}

/* select A (candidate vs fallback); fallback per-image means reduced from
   pbsum here. */
__global__ __launch_bounds__(256) void k_selA(const unsigned* __restrict__ scal,
                                              const float* __restrict__ pbsum,
                                              float* __restrict__ fscal) {
    __shared__ double simg[BATCH];
    __shared__ double ws[4];
    int t = threadIdx.x;
    int lane = t & 63, wv = t >> 6;
    for (int img = 0; img < BATCH; img++) {
        const float* p = pbsum + img * HH;
        double s = (double)p[t] + (double)p[t + 256] + (double)p[t + 512];
#pragma unroll
        for (int d = 32; d >= 1; d >>= 1) s += __shfl_down(s, (unsigned)d, 64);
        if (lane == 0) ws[wv] = s;
        __syncthreads();
        if (t == 0) simg[img] = ws[0] + ws[1] + ws[2] + ws[3];
        __syncthreads();
    }
    if (t == 0) {
        float A;
        if (scal[3]) {
            A = funkey(scal[2]);
        } else {
            double best = -1e300;
            for (int b = 0; b < BATCH; b++) {
                double m = simg[b] / (double)HW;
                if (m > best) best = m;
            }
            A = (float)best;
        }
        fscal[5] = A;
    }
}

/* final recovery, 4 pixels per thread */
__global__ __launch_bounds__(256) void k_final(const float* __restrict__ x,
                                               const float* __restrict__ V1,
                                               const float* __restrict__ fscal,
                                               float* __restrict__ out) {
    float A = fscal[5];
    float invA = 1.0f / A;
    int i = (blockIdx.x * 256 + threadIdx.x) * 4;  /* 0..NPIX-4 */
    int b = i / HW;
    int pix = i - b * HW;
    float4 v1 = *(const float4*)(V1 + i);
    float4 v1c, den;
    v1c.x = fminf(v1.x * 0.95f, 0.8f); den.x = 1.0f / (1.0f - v1c.x * invA);
    v1c.y = fminf(v1.y * 0.95f, 0.8f); den.y = 1.0f / (1.0f - v1c.y * invA);
    v1c.z = fminf(v1.z * 0.95f, 0.8f); den.z = 1.0f / (1.0f - v1c.z * invA);
    v1c.w = fminf(v1.w * 0.95f, 0.8f); den.w = 1.0f / (1.0f - v1c.w * invA);
    size_t o = (size_t)b * 3 * HW + pix;
#pragma unroll
    for (int c = 0; c < 3; c++) {
        float4 m = *(const float4*)(x + o);
        float4 y;
        y.x = fminf(fmaxf((m.x * 255.0f - v1c.x) * den.x, 0.0f), 1.0f);
        y.y = fminf(fmaxf((m.y * 255.0f - v1c.y) * den.y, 0.0f), 1.0f);
        y.z = fminf(fmaxf((m.z * 255.0f - v1c.z) * den.z, 0.0f), 1.0f);
        y.w = fminf(fmaxf((m.w * 255.0f - v1c.w) * den.w, 0.0f), 1.0f);
        *(float4*)(out + o) = y;
        o += HW;
    }
}

/* ---------------- launch ---------------- */

extern "C" void kernel_launch(void* const* d_in, const int* in_sizes, int n_in,
                              void* d_out, int out_size, void* d_ws, size_t ws_size,
                              hipStream_t stream) {
    const float* x = (const float*)d_in[0];
    float* out = (float*)d_out;

    unsigned* scal = (unsigned*)d_ws;                     /* [0]=minKey [1]=maxKey [2]=acandKey [3]=any */
    float* fscal = (float*)d_ws;                          /* [5]=A */
    unsigned* hist = (unsigned*)((char*)d_ws + 96);       /* [2000] */
    float* pbsum = (float*)((char*)d_ws + 8192);          /* [6144] block partials */
    float* planes = (float*)((char*)d_ws + 131072);
    float* P0 = planes + (size_t)0 * NPIX;  /* V1raw (I) */
    float* P1 = planes + (size_t)1 * NPIX;  /* mmean */
    float* P2 = planes + (size_t)2 * NPIX;  /* hmin; later HAB (with P3) */
    float* P3 = planes + (size_t)3 * NPIX;  /* p */
    float* P6 = planes + (size_t)6 * NPIX;  /* V1 */
    float4* F4 = (float4*)(planes + (size_t)4 * NPIX);    /* vertical field sums, P4..P7 */
    float2* HAB = (float2*)P2;                            /* ha,hb interleaved, P2..P3 */

    k_prep<<<NROWS, 256, 0, stream>>>(x, P0, P1, P2, pbsum, scal, hist);
    k_minv<<<BATCH * NCHM * WW / 256, 256, 0, stream>>>(P2, P3);
    k_kv1<<<NVB, 256, 0, stream>>>(P0, P3, F4);
    k_kh1<<<NROWS, 256, 0, stream>>>(F4, HAB);
    k_kv2<<<NVB, 256, 0, stream>>>(HAB, P0, P6, scal);
    k_hist<<<1024, 256, 0, stream>>>(P6, scal, hist);
    k_amax<<<1024, 256, 0, stream>>>(P6, P1, hist, scal);
    k_selA<<<1, 256, 0, stream>>>(scal, pbsum, fscal);
    k_final<<<NPIX / 1024, 256, 0, stream>>>(x, P6, fscal, out);
}